// Round 2
// baseline (277.008 us; speedup 1.0000x reference)
//
#include <hip/hip_runtime.h>

// Problem constants (fixed by the reference): K=64, C=128, H=W=512, N=150000.
typedef float v4f __attribute__((ext_vector_type(4)));

constexpr int KK = 64;
constexpr int CC = 128;

// Fused: init winner map to -1 (blocks < nInit) + transpose vertMask [K][N]
// -> vmT [N][K]. Both are independent of the scatter/produce consumers;
// stream order guarantees completion before they run.
__global__ __launch_bounds__(256) void init_transpose(
        const float* __restrict__ vm, float* __restrict__ vmT,
        int* __restrict__ winner, int N, int HW) {
    int b = blockIdx.x;
    int t = threadIdx.x;
    int nInit = (HW + 255) >> 8;
    if (b < nInit) {
        int p = b * 256 + t;
        if (p < HW) winner[p] = -1;
    }
    __shared__ float tile[KK][KK + 1];
    int n0 = b * KK;
    int lane = t & 63;   // n within tile on load, k on store
    int wv = t >> 6;     // 0..3
    int n = n0 + lane;
    #pragma unroll
    for (int r = 0; r < 16; ++r) {
        int k = r * 4 + wv;
        tile[k][lane] = (n < N) ? vm[(size_t)k * N + n] : 0.f;  // coalesced read
    }
    __syncthreads();
    #pragma unroll
    for (int r = 0; r < 16; ++r) {
        int nl = r * 4 + wv;
        int nn = n0 + nl;
        if (nn < N) vmT[(size_t)nn * KK + lane] = tile[lane][nl];  // coalesced write
    }
}

__global__ __launch_bounds__(256) void scatter_winner(
        const int* __restrict__ pX, const int* __restrict__ pY,
        const int* __restrict__ pW, int* __restrict__ winner, int N) {
    int i = blockIdx.x * 256 + threadIdx.x;
    if (i < N) {
        int idx = pY[i] * pW[0] + pX[i];
        atomicMax(&winner[idx], i);  // numpy last-write-wins == max index wins
    }
}

// One thread per pixel. Key change vs R0: UNCONDITIONAL column gather
// (clamped index, mask-scaled) so col[] promotes to 64 VGPRs instead of
// being re-fetched per channel group (R0 had VGPR_Count=36 -> spilled
// reloads -> 83us). Two channel accumulators for ILP; feature reads are
// thread-uniform -> s_load -> v_pk_fma with SGPR-pair operand.
__global__ __launch_bounds__(256, 4) void produce_T(
        const int* __restrict__ winner, const float* __restrict__ vmT,
        const float* __restrict__ feature, float* __restrict__ out, int HW) {
    int p = blockIdx.x * 256 + threadIdx.x;
    if (p >= HW) return;
    int w = winner[p];
    float m = (w >= 0) ? 1.0f : 0.0f;
    int wc = (w >= 0) ? w : 0;

    v4f col[KK / 4];
    const v4f* src = reinterpret_cast<const v4f*>(vmT + (size_t)wc * KK);
    #pragma unroll
    for (int q = 0; q < KK / 4; ++q) col[q] = src[q] * m;  // 16x dwordx4, masked once

    const v4f* f4 = reinterpret_cast<const v4f*>(feature);  // uniform -> s_load
    #pragma unroll 2
    for (int c = 0; c < CC; c += 2) {
        v4f a0 = {0.f, 0.f, 0.f, 0.f};
        v4f a1 = {0.f, 0.f, 0.f, 0.f};
        const v4f* f0 = f4 + c * (KK / 4);
        const v4f* f1 = f0 + (KK / 4);
        #pragma unroll
        for (int q = 0; q < KK / 4; ++q) {
            a0 += f0[q] * col[q];
            a1 += f1[q] * col[q];
        }
        out[(size_t)c * HW + p]       = a0[0] + a0[1] + a0[2] + a0[3];
        out[(size_t)(c + 1) * HW + p] = a1[0] + a1[1] + a1[2] + a1[3];
    }
}

extern "C" void kernel_launch(void* const* d_in, const int* in_sizes, int n_in,
                              void* d_out, int out_size, void* d_ws, size_t ws_size,
                              hipStream_t stream) {
    // inputs: 0=H(1), 1=W(1), 2=pX(N), 3=pY(N), 4=vertMask(K*N), 5=feature(C*K)
    const int* dW = (const int*)d_in[1];
    const int* pX = (const int*)d_in[2];
    const int* pY = (const int*)d_in[3];
    const float* vm = (const float*)d_in[4];
    const float* feat = (const float*)d_in[5];
    float* out = (float*)d_out;

    int N = in_sizes[2];
    int HW = out_size / CC;  // 512*512 = 262144

    int* winner = (int*)d_ws;
    size_t winBytes = (((size_t)HW * sizeof(int)) + 255) & ~(size_t)255;
    float* vmT = (float*)((char*)d_ws + winBytes);

    int nTileBlocks = (N + KK - 1) / KK;           // 2344 (>= 1024 init blocks)
    hipLaunchKernelGGL(init_transpose, dim3(nTileBlocks), dim3(256), 0, stream,
                       vm, vmT, winner, N, HW);
    hipLaunchKernelGGL(scatter_winner, dim3((N + 255) / 256), dim3(256), 0, stream,
                       pX, pY, dW, winner, N);
    hipLaunchKernelGGL(produce_T, dim3((HW + 255) / 256), dim3(256), 0, stream,
                       winner, vmT, feat, out, HW);
}

// Round 3
// 197.281 us; speedup vs baseline: 1.4041x; 1.4041x over previous
//
#include <hip/hip_runtime.h>

// NeuralFeatMap: out[128,512,512]; out[:,pY,pX] = (feature[128,64] @ vertMask[64,N]).
// Duplicate (pY,pX): numpy last-write-wins == max point index wins -> atomicMax winner map,
// then gather-GEMM: out[:,p] = feature @ vmCol[winner[p]] (zero col if no winner).
constexpr int KK = 64;
constexpr int CC = 128;

typedef float f32x4 __attribute__((ext_vector_type(4)));
typedef short short8 __attribute__((ext_vector_type(8)));
typedef unsigned short ushort_t;
typedef ushort_t ushort8 __attribute__((ext_vector_type(8)));

__device__ inline ushort_t f2bf(float f) {  // round-to-nearest-even fp32->bf16
    union { float f; unsigned u; } v; v.f = f;
    unsigned r = v.u + 0x7FFFu + ((v.u >> 16) & 1u);
    return (ushort_t)(r >> 16);
}

// vertMask [K][N] fp32 -> vmT [N][64] bf16 (contiguous 128B row per point).
__global__ __launch_bounds__(256) void transpose_bf16(
        const float* __restrict__ vm, ushort_t* __restrict__ vmT, int N) {
    __shared__ float tile[KK][KK + 1];
    int t = threadIdx.x;
    int n0 = blockIdx.x * KK;
    int lane = t & 63;
    int wv = t >> 6;  // 0..3
    int n = n0 + lane;
    #pragma unroll
    for (int r = 0; r < 16; ++r) {
        int k = r * 4 + wv;
        tile[k][lane] = (n < N) ? vm[(size_t)k * N + n] : 0.f;  // 256B coalesced
    }
    __syncthreads();
    #pragma unroll
    for (int r = 0; r < 16; ++r) {
        int nl = r * 4 + wv;
        int nn = n0 + nl;
        // tile[lane][nl]: bank = (lane*65+nl)%32 -> 2-way max (free)
        if (nn < N) vmT[(size_t)nn * KK + lane] = f2bf(tile[lane][nl]);  // 128B/wave
    }
}

__global__ __launch_bounds__(256) void scatter_winner(
        const int* __restrict__ pX, const int* __restrict__ pY,
        const int* __restrict__ pW, int* __restrict__ winner, int N) {
    int i = blockIdx.x * 256 + threadIdx.x;
    if (i < N) atomicMax(&winner[pY[i] * pW[0] + pX[i]], i);
}

// Gather-GEMM: block = 256 pixels; gather bf16 cols into LDS, then
// feature[128,64] @ cols[64,256] via mfma_f32_16x16x32_bf16.
// Wave wv owns channels [32*wv, 32*wv+32). Layouts (HW-verified):
//   A[m=lane&15][k=quad*8+j]  B[k=quad*8+j][n=lane&15]  C: col=lane&15,row=quad*4+reg
__global__ __launch_bounds__(256, 4) void produce_mfma(
        const int* __restrict__ winner, const ushort_t* __restrict__ vmT,
        const float* __restrict__ feature, float* __restrict__ out, int HW) {
    __shared__ ushort_t ldsB[256][72];  // 72 pad: bank stride 36%32=4 -> 2-way max
    int t = threadIdx.x;
    int p0 = blockIdx.x * 256;
    int wv = t >> 6;
    int L = t & 63;
    int lm = L & 15, q = L >> 4;
    int m0 = wv * 32;

    // A fragments: feature fp32 -> bf16, 8 contiguous elems per (mt,kh). Once per thread.
    short8 afrag[2][2];
    #pragma unroll
    for (int mt = 0; mt < 2; ++mt)
        #pragma unroll
        for (int kh = 0; kh < 2; ++kh) {
            const float* fp = feature + (size_t)(m0 + mt * 16 + lm) * KK + kh * 32 + q * 8;
            f32x4 x0 = *(const f32x4*)fp;
            f32x4 x1 = *(const f32x4*)(fp + 4);
            short8 s;
            s[0] = (short)f2bf(x0[0]); s[1] = (short)f2bf(x0[1]);
            s[2] = (short)f2bf(x0[2]); s[3] = (short)f2bf(x0[3]);
            s[4] = (short)f2bf(x1[0]); s[5] = (short)f2bf(x1[1]);
            s[6] = (short)f2bf(x1[2]); s[7] = (short)f2bf(x1[3]);
            afrag[mt][kh] = s;
        }

    // Gather: thread t -> pixel p0+t's column (128B, 8x dwordx4), or zeros.
    int w = (p0 + t < HW) ? winner[p0 + t] : -1;
    if (w >= 0) {
        const ushort8* src = (const ushort8*)(vmT + (size_t)w * KK);
        #pragma unroll
        for (int i = 0; i < 8; ++i) *(ushort8*)&ldsB[t][i * 8] = src[i];
    } else {
        ushort8 z = {0, 0, 0, 0, 0, 0, 0, 0};
        #pragma unroll
        for (int i = 0; i < 8; ++i) *(ushort8*)&ldsB[t][i * 8] = z;
    }
    __syncthreads();

    #pragma unroll 4
    for (int nt = 0; nt < 16; ++nt) {
        short8 b0 = *(const short8*)&ldsB[nt * 16 + lm][q * 8];       // ds_read_b128
        short8 b1 = *(const short8*)&ldsB[nt * 16 + lm][32 + q * 8];
        f32x4 acc0 = {0.f, 0.f, 0.f, 0.f};
        f32x4 acc1 = {0.f, 0.f, 0.f, 0.f};
        acc0 = __builtin_amdgcn_mfma_f32_16x16x32_bf16(afrag[0][0], b0, acc0, 0, 0, 0);
        acc0 = __builtin_amdgcn_mfma_f32_16x16x32_bf16(afrag[0][1], b1, acc0, 0, 0, 0);
        acc1 = __builtin_amdgcn_mfma_f32_16x16x32_bf16(afrag[1][0], b0, acc1, 0, 0, 0);
        acc1 = __builtin_amdgcn_mfma_f32_16x16x32_bf16(afrag[1][1], b1, acc1, 0, 0, 0);
        int pc = p0 + nt * 16 + lm;
        #pragma unroll
        for (int r = 0; r < 4; ++r) {
            out[(size_t)(m0 + q * 4 + r) * HW + pc] = acc0[r];
            out[(size_t)(m0 + 16 + q * 4 + r) * HW + pc] = acc1[r];
        }
    }
}

extern "C" void kernel_launch(void* const* d_in, const int* in_sizes, int n_in,
                              void* d_out, int out_size, void* d_ws, size_t ws_size,
                              hipStream_t stream) {
    // inputs: 0=H(1), 1=W(1), 2=pX(N), 3=pY(N), 4=vertMask(K*N), 5=feature(C*K)
    const int* dW = (const int*)d_in[1];
    const int* pX = (const int*)d_in[2];
    const int* pY = (const int*)d_in[3];
    const float* vm = (const float*)d_in[4];
    const float* feat = (const float*)d_in[5];
    float* out = (float*)d_out;

    int N = in_sizes[2];
    int HW = out_size / CC;  // 262144

    int* winner = (int*)d_ws;
    size_t winBytes = (((size_t)HW * sizeof(int)) + 255) & ~(size_t)255;
    ushort_t* vmT = (ushort_t*)((char*)d_ws + winBytes);

    hipMemsetAsync(winner, 0xFF, (size_t)HW * sizeof(int), stream);  // winner = -1
    hipLaunchKernelGGL(transpose_bf16, dim3((N + KK - 1) / KK), dim3(256), 0, stream,
                       vm, vmT, N);
    hipLaunchKernelGGL(scatter_winner, dim3((N + 255) / 256), dim3(256), 0, stream,
                       pX, pY, dW, winner, N);
    hipLaunchKernelGGL(produce_mfma, dim3(HW / 256), dim3(256), 0, stream,
                       winner, vmT, feat, out, HW);
}